// Round 5
// baseline (251.361 us; speedup 1.0000x reference)
//
#include <hip/hip_runtime.h>
#include <hip/hip_bf16.h>

typedef _Float16 f16;
typedef _Float16 f16x8 __attribute__((ext_vector_type(8)));
typedef _Float16 f16x4 __attribute__((ext_vector_type(4)));
typedef float f32x4 __attribute__((ext_vector_type(4)));

constexpr int Bb = 8, Ss = 1024, Hh = 16, DH = 64, DM = 1024, N3 = 3072;
constexpr int Mm = Bb * Ss;  // 8192
constexpr float EPS = 1.1920929e-07f;
constexpr float NEG = -1e30f;

// async global->LDS, 16B per lane; LDS dest is wave-uniform base + lane*16
__device__ __forceinline__ void gll16(const f16* g, f16* l) {
    __builtin_amdgcn_global_load_lds(
        (__attribute__((address_space(1))) void*)(g),
        (__attribute__((address_space(3))) void*)(l), 16, 0, 0);
}

// ---------------- K0: fused RMSNorm + cast -> xh (f16) ----------------
__global__ void rmscast_kernel(const float* __restrict__ x, f16* __restrict__ xh) {
    const int row = blockIdx.x;
    const int t = threadIdx.x;  // 256
    float4 v = *(const float4*)(x + (size_t)row * DM + t * 4);
    float s = v.x * v.x + v.y * v.y + v.z * v.z + v.w * v.w;
#pragma unroll
    for (int o = 32; o > 0; o >>= 1) s += __shfl_down(s, o, 64);
    __shared__ float red[4];
    if ((t & 63) == 0) red[t >> 6] = s;
    __syncthreads();
    float tot = red[0] + red[1] + red[2] + red[3];
    float sc = rsqrtf(tot * (1.0f / DM) + EPS);
    f16x4 hv = {(f16)(v.x * sc), (f16)(v.y * sc), (f16)(v.z * sc), (f16)(v.w * sc)};
    *(f16x4*)(xh + (size_t)row * DM + t * 4) = hv;
}

// ---------------- K1: weight casts fp32 -> fp16 (vectorized) ----------------
__global__ void castw_kernel(const float* __restrict__ Wqkv, const float* __restrict__ Wo,
                             f16* __restrict__ wq, f16* __restrict__ wo) {
    int i = blockIdx.x * 256 + threadIdx.x;  // group of 4 elements
    const int n1 = (N3 * DM) / 4;
    if (i < n1) {
        float4 v = ((const float4*)Wqkv)[i];
        f16x4 h = {(f16)v.x, (f16)v.y, (f16)v.z, (f16)v.w};
        ((f16x4*)wq)[i] = h;
    } else {
        int j = i - n1;
        float4 v = ((const float4*)Wo)[j];
        f16x4 h = {(f16)v.x, (f16)v.y, (f16)v.z, (f16)v.w};
        ((f16x4*)wo)[j] = h;
    }
}

// ---------------- K2: QKV GEMM (m97 structure: gll16 + XOR swizzle) ----------------
__launch_bounds__(256, 2)
__global__ void qkv_gemm(const f16* __restrict__ xh, const f16* __restrict__ wq,
                         const float* __restrict__ bqkv, f16* __restrict__ qk,
                         f16* __restrict__ vT) {
    __shared__ __align__(16) f16 As[128 * 64];
    __shared__ __align__(16) f16 Bs[128 * 64];
    const int t = threadIdx.x, lane = t & 63, w = t >> 6;
    const int gm0 = blockIdx.y * 128, gn0 = blockIdx.x * 128;
    const int wm = (w >> 1) * 64, wn = (w & 1) * 64;
    const int srow = lane >> 3, sslot = (lane & 7) ^ srow;
    const int r15 = lane & 15, cs = lane >> 4;

    const f16* Ag = xh + (size_t)(gm0 + srow) * DM + sslot * 8;
    const f16* Bg = wq + (size_t)(gn0 + srow) * DM + sslot * 8;

    int aoff[4][2], boff[4][2];
#pragma unroll
    for (int i = 0; i < 4; ++i) {
        int Ra = wm + i * 16 + r15;
        aoff[i][0] = Ra * 64 + ((cs ^ (Ra & 7)) * 8);
        aoff[i][1] = Ra * 64 + (((cs + 4) ^ (Ra & 7)) * 8);
        int Rb = wn + i * 16 + r15;
        boff[i][0] = Rb * 64 + ((cs ^ (Rb & 7)) * 8);
        boff[i][1] = Rb * 64 + (((cs + 4) ^ (Rb & 7)) * 8);
    }
    f32x4 acc[4][4] = {};

    for (int k0 = 0; k0 < DM; k0 += 64) {
        __syncthreads();
#pragma unroll
        for (int j = 0; j < 4; ++j) {
            int c = w * 4 + j;
            gll16(Ag + (size_t)c * 8 * DM + k0, As + c * 512);
            gll16(Bg + (size_t)c * 8 * DM + k0, Bs + c * 512);
        }
        __syncthreads();
#pragma unroll
        for (int half = 0; half < 2; ++half) {
            f16x8 af[4], bf[4];
#pragma unroll
            for (int i = 0; i < 4; ++i) af[i] = *(const f16x8*)&As[aoff[i][half]];
#pragma unroll
            for (int i = 0; i < 4; ++i) bf[i] = *(const f16x8*)&Bs[boff[i][half]];
#pragma unroll
            for (int mi = 0; mi < 4; ++mi)
#pragma unroll
                for (int ni = 0; ni < 4; ++ni)
                    acc[mi][ni] = __builtin_amdgcn_mfma_f32_16x16x32_f16(af[mi], bf[ni], acc[mi][ni], 0, 0, 0);
        }
    }
#pragma unroll
    for (int mi = 0; mi < 4; ++mi) {
#pragma unroll
        for (int ni = 0; ni < 4; ++ni) {
            int jcol = gn0 + wn + ni * 16 + r15;
            float bb = bqkv[jcol];
            int h = jcol / 192, r = jcol % 192;
            int d = r / 3, which = r % 3;
            int m0 = gm0 + wm + mi * 16 + cs * 4;
            int b = m0 >> 10, s0 = m0 & 1023;
            int bh = b * Hh + h;
            if (which == 2) {
                f16x4 pv = {(f16)(acc[mi][ni][0] + bb), (f16)(acc[mi][ni][1] + bb),
                            (f16)(acc[mi][ni][2] + bb), (f16)(acc[mi][ni][3] + bb)};
                *(f16x4*)(vT + ((size_t)bh * DH + d) * Ss + s0) = pv;
            } else {
                size_t base = ((size_t)which * (Bb * Hh) + bh) * (size_t)(Ss * DH) + (size_t)s0 * DH + d;
#pragma unroll
                for (int jj = 0; jj < 4; ++jj)
                    qk[base + (size_t)jj * DH] = (f16)(acc[mi][ni][jj] + bb);
            }
        }
    }
}

// ---------------- K3a: column stats, KBLK=128, 8 waves, dbuf Q ----------------
// grid: x=8 (k-tile of 128), y=128 (b*h)
__launch_bounds__(512, 4)
__global__ void colstats_kernel(const f16* __restrict__ qk, float* __restrict__ cbuf) {
    __shared__ __align__(16) f16 Ks[128 * 64];
    __shared__ __align__(16) f16 Qs[2][64 * 64];
    const int t = threadIdx.x, lane = t & 63, w = t >> 6;
    const int r15 = lane & 15, cs = lane >> 4;
    const int srow = lane >> 3, sslot = (lane & 7) ^ srow;
    const int bh = blockIdx.y, kt = blockIdx.x;
    const size_t hs = (size_t)(Bb * Hh) * (Ss * DH);
    const f16* qb = qk + (size_t)bh * (Ss * DH);
    const f16* kb = qb + hs;
    const int qt0 = 2 * kt;

    // stage K 128x64 (2 chunks/wave) + first Q tile (1 chunk/wave)
    gll16(kb + (size_t)(kt * 128 + w * 16 + srow) * DH + sslot * 8, Ks + (2 * w) * 512);
    gll16(kb + (size_t)(kt * 128 + w * 16 + 8 + srow) * DH + sslot * 8, Ks + (2 * w + 1) * 512);
    gll16(qb + (size_t)(qt0 * 64 + w * 8 + srow) * DH + sslot * 8, Qs[0] + w * 512);
    __syncthreads();
    const int Rk = w * 16 + r15;
    f16x8 b0 = *(const f16x8*)&Ks[Rk * 64 + ((cs ^ (Rk & 7)) * 8)];
    f16x8 b1 = *(const f16x8*)&Ks[Rk * 64 + (((cs + 4) ^ (Rk & 7)) * 8)];
    float m_run = NEG, l_run = 0.0f;
    const int kwave = kt * 128 + w * 16;
    const int kglob = kwave + r15;
    int cur = 0;

    for (int qt = qt0; qt < 16; ++qt) {
        if (qt + 1 < 16)  // prefetch next Q tile into other buffer
            gll16(qb + (size_t)((qt + 1) * 64 + w * 8 + srow) * DH + sslot * 8,
                  Qs[cur ^ 1] + w * 512);
        if (qt * 64 + 63 >= kwave) {
            float sv[16];
#pragma unroll
            for (int qs = 0; qs < 4; ++qs) {
                if (qt * 64 + qs * 16 + 15 < kwave) {
#pragma unroll
                    for (int jj = 0; jj < 4; ++jj) sv[qs * 4 + jj] = NEG;
                    continue;
                }
                int Ra = qs * 16 + r15;
                f16x8 a0 = *(const f16x8*)&Qs[cur][Ra * 64 + ((cs ^ (Ra & 7)) * 8)];
                f16x8 a1 = *(const f16x8*)&Qs[cur][Ra * 64 + (((cs + 4) ^ (Ra & 7)) * 8)];
                f32x4 sf = {};
                sf = __builtin_amdgcn_mfma_f32_16x16x32_f16(a0, b0, sf, 0, 0, 0);
                sf = __builtin_amdgcn_mfma_f32_16x16x32_f16(a1, b1, sf, 0, 0, 0);
#pragma unroll
                for (int jj = 0; jj < 4; ++jj) {
                    int q = qt * 64 + qs * 16 + cs * 4 + jj;
                    sv[qs * 4 + jj] = (q >= kglob) ? sf[jj] : NEG;
                }
            }
            float tmax = sv[0];
#pragma unroll
            for (int i = 1; i < 16; ++i) tmax = fmaxf(tmax, sv[i]);
            tmax = fmaxf(tmax, __shfl_xor(tmax, 16, 64));
            tmax = fmaxf(tmax, __shfl_xor(tmax, 32, 64));
            float m_new = fmaxf(m_run, tmax);
            float ssum = 0.0f;
#pragma unroll
            for (int i = 0; i < 16; ++i) ssum += __expf(sv[i] - m_new);
            ssum += __shfl_xor(ssum, 16, 64);
            ssum += __shfl_xor(ssum, 32, 64);
            l_run = l_run * __expf(m_run - m_new) + ssum;  // NEG sentinel washes junk
            m_run = m_new;
        }
        __syncthreads();  // drains prefetch vmcnt + protects Qs[cur^1]
        cur ^= 1;
    }
    if (cs == 0) cbuf[bh * Ss + kglob] = m_run + logf(l_run);
}

// ---------------- K3b: attnz, QBLK=128, 8 waves, dbuf K/V ----------------
// grid: x=8 (q-tile of 128, longest first), y=128 (b*h)
__launch_bounds__(512, 4)
__global__ void attnz_kernel(const f16* __restrict__ qk, const f16* __restrict__ vT,
                             const float* __restrict__ cbuf, f16* __restrict__ z) {
    __shared__ __align__(16) f16 Qs[128 * 64];
    __shared__ __align__(16) f16 Ks[2][64 * 64];
    __shared__ __align__(16) f16 Vs[2][64 * 64];  // [d][k-local]
    __shared__ f16 Pl[8][16][72];
    const int t = threadIdx.x, lane = t & 63, w = t >> 6;
    const int r15 = lane & 15, cs = lane >> 4;
    const int srow = lane >> 3, sslot = (lane & 7) ^ srow;
    const int bh = blockIdx.y, qt = 7 - blockIdx.x;  // longest first
    const size_t hs = (size_t)(Bb * Hh) * (Ss * DH);
    const f16* qb = qk + (size_t)bh * (Ss * DH);
    const f16* kb = qb + hs;
    const f16* vb = vT + (size_t)bh * (DH * Ss);

    // stage Q 128x64 (2 chunks/wave) + K/V tile 0 (1 chunk/wave each)
    gll16(qb + (size_t)(qt * 128 + w * 16 + srow) * DH + sslot * 8, Qs + (2 * w) * 512);
    gll16(qb + (size_t)(qt * 128 + w * 16 + 8 + srow) * DH + sslot * 8, Qs + (2 * w + 1) * 512);
    gll16(kb + (size_t)(w * 8 + srow) * DH + sslot * 8, Ks[0] + w * 512);
    gll16(vb + (size_t)(w * 8 + srow) * Ss + sslot * 8, Vs[0] + w * 512);
    __syncthreads();
    const int Rq = w * 16 + r15;
    f16x8 aq0 = *(const f16x8*)&Qs[Rq * 64 + ((cs ^ (Rq & 7)) * 8)];
    f16x8 aq1 = *(const f16x8*)&Qs[Rq * 64 + (((cs + 4) ^ (Rq & 7)) * 8)];
    f32x4 acc[4] = {};
    const int qw = qt * 128 + w * 16;
    const int nkt = 2 * qt + 2;
    int cur = 0;

    for (int kt = 0; kt < nkt; ++kt) {
        if (kt + 1 < nkt) {  // prefetch next K/V tile into other buffer
            gll16(kb + (size_t)((kt + 1) * 64 + w * 8 + srow) * DH + sslot * 8,
                  Ks[cur ^ 1] + w * 512);
            gll16(vb + (size_t)(w * 8 + srow) * Ss + (kt + 1) * 64 + sslot * 8,
                  Vs[cur ^ 1] + w * 512);
        }
        if (kt * 64 <= qw + 15) {  // wave has unmasked work
#pragma unroll
            for (int ck = 0; ck < 4; ++ck) {
                int kmin = kt * 64 + ck * 16;
                if (kmin > qw + 15) {
#pragma unroll
                    for (int jj = 0; jj < 4; ++jj)
                        Pl[w][cs * 4 + jj][ck * 16 + r15] = (f16)0.0f;
                    continue;
                }
                int Rb = ck * 16 + r15;
                f16x8 b0 = *(const f16x8*)&Ks[cur][Rb * 64 + ((cs ^ (Rb & 7)) * 8)];
                f16x8 b1 = *(const f16x8*)&Ks[cur][Rb * 64 + (((cs + 4) ^ (Rb & 7)) * 8)];
                f32x4 sf = {};
                sf = __builtin_amdgcn_mfma_f32_16x16x32_f16(aq0, b0, sf, 0, 0, 0);
                sf = __builtin_amdgcn_mfma_f32_16x16x32_f16(aq1, b1, sf, 0, 0, 0);
                int kg = kmin + r15;
                float ckv = cbuf[bh * Ss + kg];
                const bool needmask = (kmin + 15 > qw);
#pragma unroll
                for (int jj = 0; jj < 4; ++jj) {
                    int q = qw + cs * 4 + jj;
                    float p = (!needmask || kg <= q) ? __expf(sf[jj] - ckv) : 0.0f;
                    Pl[w][cs * 4 + jj][ck * 16 + r15] = (f16)p;
                }
            }
            f16x8 pa0 = *(const f16x8*)&Pl[w][r15][cs * 8];
            f16x8 pa1 = *(const f16x8*)&Pl[w][r15][32 + cs * 8];
#pragma unroll
            for (int dk = 0; dk < 4; ++dk) {
                int Rv = dk * 16 + r15;
                f16x8 bv0 = *(const f16x8*)&Vs[cur][Rv * 64 + ((cs ^ (Rv & 7)) * 8)];
                f16x8 bv1 = *(const f16x8*)&Vs[cur][Rv * 64 + (((cs + 4) ^ (Rv & 7)) * 8)];
                acc[dk] = __builtin_amdgcn_mfma_f32_16x16x32_f16(pa0, bv0, acc[dk], 0, 0, 0);
                acc[dk] = __builtin_amdgcn_mfma_f32_16x16x32_f16(pa1, bv1, acc[dk], 0, 0, 0);
            }
        }
        __syncthreads();  // drains prefetch vmcnt + protects buffers
        cur ^= 1;
    }
    const int b = bh >> 4, h = bh & 15;
#pragma unroll
    for (int dk = 0; dk < 4; ++dk) {
#pragma unroll
        for (int jj = 0; jj < 4; ++jj) {
            int q = qw + cs * 4 + jj;
            int d = dk * 16 + r15;
            z[((size_t)(b * Ss + q)) * DM + h * DH + d] = (f16)acc[dk][jj];
        }
    }
}

// ---------------- K4: output projection (m97 structure) ----------------
__launch_bounds__(256, 2)
__global__ void out_gemm(const f16* __restrict__ z, const f16* __restrict__ wo,
                         const float* __restrict__ bo, float* __restrict__ out) {
    __shared__ __align__(16) f16 As[128 * 64];
    __shared__ __align__(16) f16 Bs[128 * 64];
    const int t = threadIdx.x, lane = t & 63, w = t >> 6;
    const int gm0 = blockIdx.y * 128, gn0 = blockIdx.x * 128;
    const int wm = (w >> 1) * 64, wn = (w & 1) * 64;
    const int srow = lane >> 3, sslot = (lane & 7) ^ srow;
    const int r15 = lane & 15, cs = lane >> 4;

    const f16* Ag = z + (size_t)(gm0 + srow) * DM + sslot * 8;
    const f16* Bg = wo + (size_t)(gn0 + srow) * DM + sslot * 8;

    int aoff[4][2], boff[4][2];
#pragma unroll
    for (int i = 0; i < 4; ++i) {
        int Ra = wm + i * 16 + r15;
        aoff[i][0] = Ra * 64 + ((cs ^ (Ra & 7)) * 8);
        aoff[i][1] = Ra * 64 + (((cs + 4) ^ (Ra & 7)) * 8);
        int Rb = wn + i * 16 + r15;
        boff[i][0] = Rb * 64 + ((cs ^ (Rb & 7)) * 8);
        boff[i][1] = Rb * 64 + (((cs + 4) ^ (Rb & 7)) * 8);
    }
    f32x4 acc[4][4] = {};

    for (int k0 = 0; k0 < DM; k0 += 64) {
        __syncthreads();
#pragma unroll
        for (int j = 0; j < 4; ++j) {
            int c = w * 4 + j;
            gll16(Ag + (size_t)c * 8 * DM + k0, As + c * 512);
            gll16(Bg + (size_t)c * 8 * DM + k0, Bs + c * 512);
        }
        __syncthreads();
#pragma unroll
        for (int half = 0; half < 2; ++half) {
            f16x8 af[4], bf[4];
#pragma unroll
            for (int i = 0; i < 4; ++i) af[i] = *(const f16x8*)&As[aoff[i][half]];
#pragma unroll
            for (int i = 0; i < 4; ++i) bf[i] = *(const f16x8*)&Bs[boff[i][half]];
#pragma unroll
            for (int mi = 0; mi < 4; ++mi)
#pragma unroll
                for (int ni = 0; ni < 4; ++ni)
                    acc[mi][ni] = __builtin_amdgcn_mfma_f32_16x16x32_f16(af[mi], bf[ni], acc[mi][ni], 0, 0, 0);
        }
    }
#pragma unroll
    for (int mi = 0; mi < 4; ++mi) {
#pragma unroll
        for (int ni = 0; ni < 4; ++ni) {
            int n = gn0 + wn + ni * 16 + r15;
            float bb = bo[n];
#pragma unroll
            for (int jj = 0; jj < 4; ++jj) {
                int m = gm0 + wm + mi * 16 + cs * 4 + jj;
                out[(size_t)m * DM + n] = acc[mi][ni][jj] + bb;
            }
        }
    }
}

extern "C" void kernel_launch(void* const* d_in, const int* in_sizes, int n_in,
                              void* d_out, int out_size, void* d_ws, size_t ws_size,
                              hipStream_t stream) {
    (void)in_sizes; (void)n_in; (void)out_size; (void)ws_size;
    const float* x    = (const float*)d_in[0];
    const float* Wqkv = (const float*)d_in[1];
    const float* bqkv = (const float*)d_in[2];
    const float* Wo   = (const float*)d_in[3];
    const float* bo   = (const float*)d_in[4];
    float* out = (float*)d_out;

    char* ws = (char*)d_ws;
    f16* xh   = (f16*)ws;                       // 16,777,216
    f16* z    = (f16*)ws;                       // reuse (xh dead after qkv_gemm)
    f16* wq   = (f16*)(ws + 16777216);          //  6,291,456
    f16* wo   = (f16*)(ws + 23068672);          //  2,097,152
    f16* qk   = (f16*)(ws + 25165824);          // 33,554,432
    f16* vT   = (f16*)(ws + 58720256);          // 16,777,216
    float* cbuf = (float*)(ws + 75497472);      //    524,288

    rmscast_kernel<<<Mm, 256, 0, stream>>>(x, xh);
    castw_kernel<<<(N3 * DM + DM * DM) / 1024, 256, 0, stream>>>(Wqkv, Wo, wq, wo);
    qkv_gemm<<<dim3(N3 / 128, Mm / 128), 256, 0, stream>>>(xh, wq, bqkv, qk, vT);
    colstats_kernel<<<dim3(8, Bb * Hh), 512, 0, stream>>>(qk, cbuf);
    attnz_kernel<<<dim3(8, Bb * Hh), 512, 0, stream>>>(qk, vT, cbuf, z);
    out_gemm<<<dim3(DM / 128, Mm / 128), 256, 0, stream>>>(z, wo, bo, out);
}

// Round 6
// 247.687 us; speedup vs baseline: 1.0148x; 1.0148x over previous
//
#include <hip/hip_runtime.h>
#include <hip/hip_bf16.h>

typedef _Float16 f16;
typedef _Float16 f16x8 __attribute__((ext_vector_type(8)));
typedef _Float16 f16x4 __attribute__((ext_vector_type(4)));
typedef float f32x4 __attribute__((ext_vector_type(4)));

constexpr int Bb = 8, Ss = 1024, Hh = 16, DH = 64, DM = 1024, N3 = 3072;
constexpr int Mm = Bb * Ss;  // 8192
constexpr float EPS = 1.1920929e-07f;
constexpr float NEG = -1e30f;

// async global->LDS, 16B per lane; LDS dest is wave-uniform base + lane*16
__device__ __forceinline__ void gll16(const f16* g, f16* l) {
    __builtin_amdgcn_global_load_lds(
        (__attribute__((address_space(1))) void*)(g),
        (__attribute__((address_space(3))) void*)(l), 16, 0, 0);
}

// ---------------- K0: fused RMSNorm + cast -> xh (f16) ----------------
__global__ void rmscast_kernel(const float* __restrict__ x, f16* __restrict__ xh) {
    const int row = blockIdx.x;
    const int t = threadIdx.x;  // 256
    float4 v = *(const float4*)(x + (size_t)row * DM + t * 4);
    float s = v.x * v.x + v.y * v.y + v.z * v.z + v.w * v.w;
#pragma unroll
    for (int o = 32; o > 0; o >>= 1) s += __shfl_down(s, o, 64);
    __shared__ float red[4];
    if ((t & 63) == 0) red[t >> 6] = s;
    __syncthreads();
    float tot = red[0] + red[1] + red[2] + red[3];
    float sc = rsqrtf(tot * (1.0f / DM) + EPS);
    f16x4 hv = {(f16)(v.x * sc), (f16)(v.y * sc), (f16)(v.z * sc), (f16)(v.w * sc)};
    *(f16x4*)(xh + (size_t)row * DM + t * 4) = hv;
}

// ---------------- K1: weight casts fp32 -> fp16 (vectorized) ----------------
__global__ void castw_kernel(const float* __restrict__ Wqkv, const float* __restrict__ Wo,
                             f16* __restrict__ wq, f16* __restrict__ wo) {
    int i = blockIdx.x * 256 + threadIdx.x;  // group of 4 elements
    const int n1 = (N3 * DM) / 4;
    if (i < n1) {
        float4 v = ((const float4*)Wqkv)[i];
        f16x4 h = {(f16)v.x, (f16)v.y, (f16)v.z, (f16)v.w};
        ((f16x4*)wq)[i] = h;
    } else {
        int j = i - n1;
        float4 v = ((const float4*)Wo)[j];
        f16x4 h = {(f16)v.x, (f16)v.y, (f16)v.z, (f16)v.w};
        ((f16x4*)wo)[j] = h;
    }
}

// ---------------- K2: QKV GEMM (m97 structure: gll16 + XOR swizzle) ----------------
__launch_bounds__(256, 2)
__global__ void qkv_gemm(const f16* __restrict__ xh, const f16* __restrict__ wq,
                         const float* __restrict__ bqkv, f16* __restrict__ qk,
                         f16* __restrict__ vT) {
    __shared__ __align__(16) f16 As[128 * 64];
    __shared__ __align__(16) f16 Bs[128 * 64];
    const int t = threadIdx.x, lane = t & 63, w = t >> 6;
    const int gm0 = blockIdx.y * 128, gn0 = blockIdx.x * 128;
    const int wm = (w >> 1) * 64, wn = (w & 1) * 64;
    const int srow = lane >> 3, sslot = (lane & 7) ^ srow;
    const int r15 = lane & 15, cs = lane >> 4;

    const f16* Ag = xh + (size_t)(gm0 + srow) * DM + sslot * 8;
    const f16* Bg = wq + (size_t)(gn0 + srow) * DM + sslot * 8;

    int aoff[4][2], boff[4][2];
#pragma unroll
    for (int i = 0; i < 4; ++i) {
        int Ra = wm + i * 16 + r15;
        aoff[i][0] = Ra * 64 + ((cs ^ (Ra & 7)) * 8);
        aoff[i][1] = Ra * 64 + (((cs + 4) ^ (Ra & 7)) * 8);
        int Rb = wn + i * 16 + r15;
        boff[i][0] = Rb * 64 + ((cs ^ (Rb & 7)) * 8);
        boff[i][1] = Rb * 64 + (((cs + 4) ^ (Rb & 7)) * 8);
    }
    f32x4 acc[4][4] = {};

    for (int k0 = 0; k0 < DM; k0 += 64) {
        __syncthreads();
#pragma unroll
        for (int j = 0; j < 4; ++j) {
            int c = w * 4 + j;
            gll16(Ag + (size_t)c * 8 * DM + k0, As + c * 512);
            gll16(Bg + (size_t)c * 8 * DM + k0, Bs + c * 512);
        }
        __syncthreads();
#pragma unroll
        for (int half = 0; half < 2; ++half) {
            f16x8 af[4], bf[4];
#pragma unroll
            for (int i = 0; i < 4; ++i) af[i] = *(const f16x8*)&As[aoff[i][half]];
#pragma unroll
            for (int i = 0; i < 4; ++i) bf[i] = *(const f16x8*)&Bs[boff[i][half]];
#pragma unroll
            for (int mi = 0; mi < 4; ++mi)
#pragma unroll
                for (int ni = 0; ni < 4; ++ni)
                    acc[mi][ni] = __builtin_amdgcn_mfma_f32_16x16x32_f16(af[mi], bf[ni], acc[mi][ni], 0, 0, 0);
        }
    }
#pragma unroll
    for (int mi = 0; mi < 4; ++mi) {
#pragma unroll
        for (int ni = 0; ni < 4; ++ni) {
            int jcol = gn0 + wn + ni * 16 + r15;
            float bb = bqkv[jcol];
            int h = jcol / 192, r = jcol % 192;
            int d = r / 3, which = r % 3;
            int m0 = gm0 + wm + mi * 16 + cs * 4;
            int b = m0 >> 10, s0 = m0 & 1023;
            int bh = b * Hh + h;
            if (which == 2) {
                f16x4 pv = {(f16)(acc[mi][ni][0] + bb), (f16)(acc[mi][ni][1] + bb),
                            (f16)(acc[mi][ni][2] + bb), (f16)(acc[mi][ni][3] + bb)};
                *(f16x4*)(vT + ((size_t)bh * DH + d) * Ss + s0) = pv;
            } else {
                size_t base = ((size_t)which * (Bb * Hh) + bh) * (size_t)(Ss * DH) + (size_t)s0 * DH + d;
#pragma unroll
                for (int jj = 0; jj < 4; ++jj)
                    qk[base + (size_t)jj * DH] = (f16)(acc[mi][ni][jj] + bb);
            }
        }
    }
}

// ---------------- K3a: column stats, KBLK=128, 8 waves, dbuf Q ----------------
// grid: x=8 (k-tile of 128), y=128 (b*h)
__launch_bounds__(512, 4)
__global__ void colstats_kernel(const f16* __restrict__ qk, float* __restrict__ cbuf) {
    __shared__ __align__(16) f16 Ks[128 * 64];
    __shared__ __align__(16) f16 Qs[2][64 * 64];
    const int t = threadIdx.x, lane = t & 63, w = t >> 6;
    const int r15 = lane & 15, cs = lane >> 4;
    const int srow = lane >> 3, sslot = (lane & 7) ^ srow;
    const int bh = blockIdx.y, kt = blockIdx.x;
    const size_t hs = (size_t)(Bb * Hh) * (Ss * DH);
    const f16* qb = qk + (size_t)bh * (Ss * DH);
    const f16* kb = qb + hs;
    const int qt0 = 2 * kt;

    gll16(kb + (size_t)(kt * 128 + w * 16 + srow) * DH + sslot * 8, Ks + (2 * w) * 512);
    gll16(kb + (size_t)(kt * 128 + w * 16 + 8 + srow) * DH + sslot * 8, Ks + (2 * w + 1) * 512);
    gll16(qb + (size_t)(qt0 * 64 + w * 8 + srow) * DH + sslot * 8, Qs[0] + w * 512);
    __syncthreads();
    const int Rk = w * 16 + r15;
    f16x8 b0 = *(const f16x8*)&Ks[Rk * 64 + ((cs ^ (Rk & 7)) * 8)];
    f16x8 b1 = *(const f16x8*)&Ks[Rk * 64 + (((cs + 4) ^ (Rk & 7)) * 8)];
    float m_run = NEG, l_run = 0.0f;
    const int kwave = kt * 128 + w * 16;
    const int kglob = kwave + r15;
    int cur = 0;

    for (int qt = qt0; qt < 16; ++qt) {
        if (qt + 1 < 16)
            gll16(qb + (size_t)((qt + 1) * 64 + w * 8 + srow) * DH + sslot * 8,
                  Qs[cur ^ 1] + w * 512);
        if (qt * 64 + 63 >= kwave) {
            float sv[16];
#pragma unroll
            for (int qs = 0; qs < 4; ++qs) {
                if (qt * 64 + qs * 16 + 15 < kwave) {
#pragma unroll
                    for (int jj = 0; jj < 4; ++jj) sv[qs * 4 + jj] = NEG;
                    continue;
                }
                int Ra = qs * 16 + r15;
                f16x8 a0 = *(const f16x8*)&Qs[cur][Ra * 64 + ((cs ^ (Ra & 7)) * 8)];
                f16x8 a1 = *(const f16x8*)&Qs[cur][Ra * 64 + (((cs + 4) ^ (Ra & 7)) * 8)];
                f32x4 sf = {};
                sf = __builtin_amdgcn_mfma_f32_16x16x32_f16(a0, b0, sf, 0, 0, 0);
                sf = __builtin_amdgcn_mfma_f32_16x16x32_f16(a1, b1, sf, 0, 0, 0);
#pragma unroll
                for (int jj = 0; jj < 4; ++jj) {
                    int q = qt * 64 + qs * 16 + cs * 4 + jj;
                    sv[qs * 4 + jj] = (q >= kglob) ? sf[jj] : NEG;
                }
            }
            float tmax = sv[0];
#pragma unroll
            for (int i = 1; i < 16; ++i) tmax = fmaxf(tmax, sv[i]);
            tmax = fmaxf(tmax, __shfl_xor(tmax, 16, 64));
            tmax = fmaxf(tmax, __shfl_xor(tmax, 32, 64));
            float m_new = fmaxf(m_run, tmax);
            float ssum = 0.0f;
#pragma unroll
            for (int i = 0; i < 16; ++i) ssum += __expf(sv[i] - m_new);
            ssum += __shfl_xor(ssum, 16, 64);
            ssum += __shfl_xor(ssum, 32, 64);
            l_run = l_run * __expf(m_run - m_new) + ssum;
            m_run = m_new;
        }
        __syncthreads();
        cur ^= 1;
    }
    if (cs == 0) cbuf[bh * Ss + kglob] = m_run + logf(l_run);
}

// ---------------- K3b: attnz, swapped QK^T, P in registers, no Pl ----------------
// grid: x=8 (q-tile of 128, longest first), y=128 (b*h); 512 thr, 36KB LDS
__launch_bounds__(512, 4)
__global__ void attnz_kernel(const f16* __restrict__ qk, const f16* __restrict__ vT,
                             const float* __restrict__ cbuf, f16* __restrict__ z) {
    __shared__ __align__(16) f16 Qs[128 * 64];  // 16KB
    __shared__ __align__(16) f16 Ks[64 * 64];   // 8KB
    __shared__ __align__(16) f16 Vs[64 * 64];   // 8KB  [d][k-local]
    __shared__ __align__(16) float cb[1024];    // 4KB
    const int t = threadIdx.x, lane = t & 63, w = t >> 6;
    const int r15 = lane & 15, cs = lane >> 4;
    const int srow = lane >> 3, sslot = (lane & 7) ^ srow;
    const int bh = blockIdx.y, qt = 7 - blockIdx.x;  // longest first
    const size_t hs = (size_t)(Bb * Hh) * (Ss * DH);
    const f16* qb = qk + (size_t)bh * (Ss * DH);
    const f16* kb = qb + hs;
    const f16* vb = vT + (size_t)bh * (DH * Ss);

    // stage Q (2 chunks/wave), K/V tile 0, and the full column-stats row
    gll16(qb + (size_t)(qt * 128 + w * 16 + srow) * DH + sslot * 8, Qs + (2 * w) * 512);
    gll16(qb + (size_t)(qt * 128 + w * 16 + 8 + srow) * DH + sslot * 8, Qs + (2 * w + 1) * 512);
    gll16(kb + (size_t)(w * 8 + srow) * DH + sslot * 8, Ks + w * 512);
    gll16(vb + (size_t)(w * 8 + srow) * Ss + sslot * 8, Vs + w * 512);
    {
        float2 c2 = *(const float2*)(cbuf + bh * Ss + t * 2);
        *(float2*)&cb[t * 2] = c2;
    }
    __syncthreads();
    const int Rq = w * 16 + r15;
    f16x8 aq0 = *(const f16x8*)&Qs[Rq * 64 + ((cs ^ (Rq & 7)) * 8)];
    f16x8 aq1 = *(const f16x8*)&Qs[Rq * 64 + (((cs + 4) ^ (Rq & 7)) * 8)];
    f32x4 acc[4] = {};
    const int qw = qt * 128 + w * 16;
    const int q = qw + r15;  // this lane's q column (S^T layout)
    const int nkt = 2 * qt + 2;

    for (int kt = 0; kt < nkt; ++kt) {
        if (kt) {
            __syncthreads();  // previous tile's reads done
            gll16(kb + (size_t)(kt * 64 + w * 8 + srow) * DH + sslot * 8, Ks + w * 512);
            gll16(vb + (size_t)(w * 8 + srow) * Ss + kt * 64 + sslot * 8, Vs + w * 512);
            __syncthreads();  // staged
        }
        if (kt * 64 > qw + 15) continue;  // wave fully masked (uniform)

        // --- S^T = K Q^T per 16k tile; P^T packed in registers ---
        unsigned pk[4][2];
#pragma unroll
        for (int tl = 0; tl < 4; ++tl) {
            int kbase = kt * 64 + tl * 16;
            if (kbase > qw + 15) { pk[tl][0] = 0u; pk[tl][1] = 0u; continue; }
            int Rk2 = tl * 16 + r15;
            f16x8 kf0 = *(const f16x8*)&Ks[Rk2 * 64 + ((cs ^ (Rk2 & 7)) * 8)];
            f16x8 kf1 = *(const f16x8*)&Ks[Rk2 * 64 + (((cs + 4) ^ (Rk2 & 7)) * 8)];
            f32x4 sf = {};
            sf = __builtin_amdgcn_mfma_f32_16x16x32_f16(kf0, aq0, sf, 0, 0, 0);
            sf = __builtin_amdgcn_mfma_f32_16x16x32_f16(kf1, aq1, sf, 0, 0, 0);
            f32x4 cv = *(const f32x4*)&cb[kbase + cs * 4];
            f16 p[4];
#pragma unroll
            for (int j = 0; j < 4; ++j) {
                int k = kbase + cs * 4 + j;
                float pv = (k <= q) ? __expf(sf[j] - cv[j]) : 0.0f;
                p[j] = (f16)pv;
            }
            union { f16 h[2]; unsigned u; } u0, u1;
            u0.h[0] = p[0]; u0.h[1] = p[1];
            u1.h[0] = p[2]; u1.h[1] = p[3];
            pk[tl][0] = u0.u; pk[tl][1] = u1.u;
        }
        // --- PV: z^T[d][q] += V^T P^T, B-frag built by bpermute + select ---
        const int sA = ((cs & 1) * 2) * 16 + r15;
        const int sB = sA + 16;
        const bool hi = (cs >> 1) != 0;
#pragma unroll
        for (int c = 0; c < 2; ++c) {
            if (kt * 64 + c * 32 > qw + 15) continue;  // uniform skip
            unsigned a0 = (unsigned)__shfl((int)pk[2 * c][0], sA, 64);
            unsigned a1 = (unsigned)__shfl((int)pk[2 * c][1], sA, 64);
            unsigned a2 = (unsigned)__shfl((int)pk[2 * c][0], sB, 64);
            unsigned a3 = (unsigned)__shfl((int)pk[2 * c][1], sB, 64);
            unsigned b0_ = (unsigned)__shfl((int)pk[2 * c + 1][0], sA, 64);
            unsigned b1_ = (unsigned)__shfl((int)pk[2 * c + 1][1], sA, 64);
            unsigned b2_ = (unsigned)__shfl((int)pk[2 * c + 1][0], sB, 64);
            unsigned b3_ = (unsigned)__shfl((int)pk[2 * c + 1][1], sB, 64);
            union { unsigned u[4]; f16x8 v; } bf;
            bf.u[0] = hi ? b0_ : a0;
            bf.u[1] = hi ? b1_ : a1;
            bf.u[2] = hi ? b2_ : a2;
            bf.u[3] = hi ? b3_ : a3;
#pragma unroll
            for (int dt = 0; dt < 4; ++dt) {
                int Rv = dt * 16 + r15;
                f16x8 vf = *(const f16x8*)&Vs[Rv * 64 + (((4 * c + cs) ^ (Rv & 7)) * 8)];
                acc[dt] = __builtin_amdgcn_mfma_f32_16x16x32_f16(vf, bf.v, acc[dt], 0, 0, 0);
            }
        }
    }
    // epilogue: lane holds z^T[d=16dt+cs*4+j][q] -> packed f16x4 store per dt
    const int b = bh >> 4, h = bh & 15;
#pragma unroll
    for (int dt = 0; dt < 4; ++dt) {
        f16x4 zv = {(f16)acc[dt][0], (f16)acc[dt][1], (f16)acc[dt][2], (f16)acc[dt][3]};
        *(f16x4*)(z + ((size_t)(b * Ss + q)) * DM + h * DH + dt * 16 + cs * 4) = zv;
    }
}

// ---------------- K4: output projection (m97 structure) ----------------
__launch_bounds__(256, 2)
__global__ void out_gemm(const f16* __restrict__ z, const f16* __restrict__ wo,
                         const float* __restrict__ bo, float* __restrict__ out) {
    __shared__ __align__(16) f16 As[128 * 64];
    __shared__ __align__(16) f16 Bs[128 * 64];
    const int t = threadIdx.x, lane = t & 63, w = t >> 6;
    const int gm0 = blockIdx.y * 128, gn0 = blockIdx.x * 128;
    const int wm = (w >> 1) * 64, wn = (w & 1) * 64;
    const int srow = lane >> 3, sslot = (lane & 7) ^ srow;
    const int r15 = lane & 15, cs = lane >> 4;

    const f16* Ag = z + (size_t)(gm0 + srow) * DM + sslot * 8;
    const f16* Bg = wo + (size_t)(gn0 + srow) * DM + sslot * 8;

    int aoff[4][2], boff[4][2];
#pragma unroll
    for (int i = 0; i < 4; ++i) {
        int Ra = wm + i * 16 + r15;
        aoff[i][0] = Ra * 64 + ((cs ^ (Ra & 7)) * 8);
        aoff[i][1] = Ra * 64 + (((cs + 4) ^ (Ra & 7)) * 8);
        int Rb = wn + i * 16 + r15;
        boff[i][0] = Rb * 64 + ((cs ^ (Rb & 7)) * 8);
        boff[i][1] = Rb * 64 + (((cs + 4) ^ (Rb & 7)) * 8);
    }
    f32x4 acc[4][4] = {};

    for (int k0 = 0; k0 < DM; k0 += 64) {
        __syncthreads();
#pragma unroll
        for (int j = 0; j < 4; ++j) {
            int c = w * 4 + j;
            gll16(Ag + (size_t)c * 8 * DM + k0, As + c * 512);
            gll16(Bg + (size_t)c * 8 * DM + k0, Bs + c * 512);
        }
        __syncthreads();
#pragma unroll
        for (int half = 0; half < 2; ++half) {
            f16x8 af[4], bf[4];
#pragma unroll
            for (int i = 0; i < 4; ++i) af[i] = *(const f16x8*)&As[aoff[i][half]];
#pragma unroll
            for (int i = 0; i < 4; ++i) bf[i] = *(const f16x8*)&Bs[boff[i][half]];
#pragma unroll
            for (int mi = 0; mi < 4; ++mi)
#pragma unroll
                for (int ni = 0; ni < 4; ++ni)
                    acc[mi][ni] = __builtin_amdgcn_mfma_f32_16x16x32_f16(af[mi], bf[ni], acc[mi][ni], 0, 0, 0);
        }
    }
#pragma unroll
    for (int mi = 0; mi < 4; ++mi) {
#pragma unroll
        for (int ni = 0; ni < 4; ++ni) {
            int n = gn0 + wn + ni * 16 + r15;
            float bb = bo[n];
#pragma unroll
            for (int jj = 0; jj < 4; ++jj) {
                int m = gm0 + wm + mi * 16 + cs * 4 + jj;
                out[(size_t)m * DM + n] = acc[mi][ni][jj] + bb;
            }
        }
    }
}

extern "C" void kernel_launch(void* const* d_in, const int* in_sizes, int n_in,
                              void* d_out, int out_size, void* d_ws, size_t ws_size,
                              hipStream_t stream) {
    (void)in_sizes; (void)n_in; (void)out_size; (void)ws_size;
    const float* x    = (const float*)d_in[0];
    const float* Wqkv = (const float*)d_in[1];
    const float* bqkv = (const float*)d_in[2];
    const float* Wo   = (const float*)d_in[3];
    const float* bo   = (const float*)d_in[4];
    float* out = (float*)d_out;

    char* ws = (char*)d_ws;
    f16* xh   = (f16*)ws;                       // 16,777,216
    f16* z    = (f16*)ws;                       // reuse (xh dead after qkv_gemm)
    f16* wq   = (f16*)(ws + 16777216);          //  6,291,456
    f16* wo   = (f16*)(ws + 23068672);          //  2,097,152
    f16* qk   = (f16*)(ws + 25165824);          // 33,554,432
    f16* vT   = (f16*)(ws + 58720256);          // 16,777,216
    float* cbuf = (float*)(ws + 75497472);      //    524,288

    rmscast_kernel<<<Mm, 256, 0, stream>>>(x, xh);
    castw_kernel<<<(N3 * DM + DM * DM) / 1024, 256, 0, stream>>>(Wqkv, Wo, wq, wo);
    qkv_gemm<<<dim3(N3 / 128, Mm / 128), 256, 0, stream>>>(xh, wq, bqkv, qk, vT);
    colstats_kernel<<<dim3(8, Bb * Hh), 512, 0, stream>>>(qk, cbuf);
    attnz_kernel<<<dim3(8, Bb * Hh), 512, 0, stream>>>(qk, vT, cbuf, z);
    out_gemm<<<dim3(DM / 128, Mm / 128), 256, 0, stream>>>(z, wo, bo, out);
}